// Round 1
// baseline (934.090 us; speedup 1.0000x reference)
//
#include <hip/hip_runtime.h>
#include <math.h>

#define D_IN 768
#define E_DIM 256
#define NB 32
#define NP 192
#define NA 30
#define PC 16
#define PS_STRIDE 260
#define XS_STRIDE 36

// ---------------------------------------------------------------------------
// Projection GEMM: Y[m][e] = sum_k X[srow(m)][k] * W[e][k] + b[e]
// grid = 224 blocks: [0,192) patch, [192,222) att, 222 vis, 223 txt
// tile: 32 rows x 256 cols, K staged in chunks of 32.
// ---------------------------------------------------------------------------
__global__ __launch_bounds__(256) void proj_kernel(
    const float* __restrict__ vf, const float* __restrict__ tf,
    const float* __restrict__ Wv, const float* __restrict__ bv,
    const float* __restrict__ Wt, const float* __restrict__ bt,
    const float* __restrict__ Wp, const float* __restrict__ bp,
    const float* __restrict__ Wa, const float* __restrict__ ba,
    float* __restrict__ out_vis, float* __restrict__ out_txt,
    float* __restrict__ patch, float* __restrict__ att)
{
    __shared__ float Xs[32 * 36];    // Xs[k][m], padded stride 36
    __shared__ float Ws[32 * 260];   // Ws[k][e], padded stride 260

    const int bid = blockIdx.x;
    const float *X, *W, *bias;
    float* Y;
    int m0, RPB, TPB, TOFF;
    if (bid < 192)       { X = vf; W = Wp; bias = bp; Y = patch;   m0 = bid * 32;         RPB = 192; TPB = 193; TOFF = 1; }
    else if (bid < 222)  { X = tf; W = Wa; bias = ba; Y = att;     m0 = (bid - 192) * 32; RPB = 30;  TPB = 31;  TOFF = 1; }
    else if (bid == 222) { X = vf; W = Wv; bias = bv; Y = out_vis; m0 = 0;                RPB = 1;   TPB = 193; TOFF = 0; }
    else                 { X = tf; W = Wt; bias = bt; Y = out_txt; m0 = 0;                RPB = 1;   TPB = 31;  TOFF = 0; }

    const int tid = threadIdx.x;
    const int et  = tid & 63;     // e-thread
    const int mg  = tid >> 6;     // m-group (wave id)
    const int e0  = et * 4;
    const int m0l = mg * 8;

    // staging roles
    const int k4 = tid & 7;       // k quad
    const int sm = tid >> 3;      // 0..31 (m for X stage, e-base for W stage)

    // fixed source row for X staging
    const int r = m0 + sm;
    const int batch = r / RPB;
    const int idx = r - batch * RPB;
    const float* xrow = X + (batch * TPB + TOFF + idx) * D_IN;

    float acc[8][4];
    #pragma unroll
    for (int i = 0; i < 8; ++i) {
        #pragma unroll
        for (int c = 0; c < 4; ++c) acc[i][c] = 0.f;
    }

    for (int kk = 0; kk < D_IN; kk += 32) {
        // stage X tile transposed: Xs[k][m]
        {
            float4 xv = *(const float4*)&xrow[kk + k4 * 4];
            Xs[(k4 * 4 + 0) * 36 + sm] = xv.x;
            Xs[(k4 * 4 + 1) * 36 + sm] = xv.y;
            Xs[(k4 * 4 + 2) * 36 + sm] = xv.z;
            Xs[(k4 * 4 + 3) * 36 + sm] = xv.w;
        }
        // stage W tile transposed: Ws[k][e]
        #pragma unroll
        for (int j = 0; j < 8; ++j) {
            const int e = sm + 32 * j;
            float4 wv = *(const float4*)&W[e * D_IN + kk + k4 * 4];
            Ws[(k4 * 4 + 0) * 260 + e] = wv.x;
            Ws[(k4 * 4 + 1) * 260 + e] = wv.y;
            Ws[(k4 * 4 + 2) * 260 + e] = wv.z;
            Ws[(k4 * 4 + 3) * 260 + e] = wv.w;
        }
        __syncthreads();
        #pragma unroll
        for (int k = 0; k < 32; ++k) {
            float4 w  = *(const float4*)&Ws[k * 260 + e0];
            float4 x0 = *(const float4*)&Xs[k * 36 + m0l];
            float4 x1 = *(const float4*)&Xs[k * 36 + m0l + 4];
            float xs[8] = {x0.x, x0.y, x0.z, x0.w, x1.x, x1.y, x1.z, x1.w};
            #pragma unroll
            for (int mi = 0; mi < 8; ++mi) {
                acc[mi][0] += xs[mi] * w.x;
                acc[mi][1] += xs[mi] * w.y;
                acc[mi][2] += xs[mi] * w.z;
                acc[mi][3] += xs[mi] * w.w;
            }
        }
        __syncthreads();
    }

    float4 bvv = *(const float4*)&bias[e0];
    #pragma unroll
    for (int mi = 0; mi < 8; ++mi) {
        float4 st;
        st.x = acc[mi][0] + bvv.x;
        st.y = acc[mi][1] + bvv.y;
        st.z = acc[mi][2] + bvv.z;
        st.w = acc[mi][3] + bvv.w;
        *(float4*)&Y[(m0 + m0l + mi) * E_DIM + e0] = st;
    }
}

// ---------------------------------------------------------------------------
// Row inverse-norms: invp[6144] for patch rows, inva[960] for att rows.
// 1 wave per row, 4 rows per block. grid = 1776.
// ---------------------------------------------------------------------------
__global__ __launch_bounds__(256) void norm_kernel(
    const float* __restrict__ patch, const float* __restrict__ att,
    float* __restrict__ invp, float* __restrict__ inva)
{
    const int row  = blockIdx.x * 4 + (threadIdx.x >> 6);
    const int lane = threadIdx.x & 63;
    const float* src;
    float* dst;
    if (row < NB * NP) { src = patch + row * E_DIM;            dst = invp + row; }
    else               { src = att + (row - NB * NP) * E_DIM;  dst = inva + (row - NB * NP); }

    float4 xv = *(const float4*)&src[lane * 4];
    float ssq = xv.x * xv.x + xv.y * xv.y + xv.z * xv.z + xv.w * xv.w;
    #pragma unroll
    for (int off = 32; off >= 1; off >>= 1) ssq += __shfl_xor(ssq, off, 64);
    if (lane == 0) *dst = 1.f / fmaxf(sqrtf(ssq), 1e-12f);
}

// ---------------------------------------------------------------------------
// Means: patch_mean (bid<32) and att_mean (bid>=32). grid = 64.
// ---------------------------------------------------------------------------
__global__ __launch_bounds__(256) void mean_kernel(
    const float* __restrict__ patch, const float* __restrict__ att,
    const int* __restrict__ att_nums,
    float* __restrict__ out_pm, float* __restrict__ out_am)
{
    const int tid = threadIdx.x;
    if (blockIdx.x < 32) {
        const int v = blockIdx.x;
        float s = 0.f;
        for (int p = 0; p < NP; ++p) s += patch[(v * NP + p) * E_DIM + tid];
        out_pm[v * E_DIM + tid] = s * (1.f / (float)NP);
    } else {
        const int t = blockIdx.x - 32;
        float s = 0.f;
        #pragma unroll
        for (int a = 0; a < NA; ++a) s += att[(t * NA + a) * E_DIM + tid];
        out_am[t * E_DIM + tid] = s / (float)att_nums[t];
    }
}

// ---------------------------------------------------------------------------
// Pair kernel: one block per (v,t). Computes local_similarity[t][v].
//   X[p,a] = exp(relu(20 * cos(patch_p, att_a)))   (exact softmax w/o max-sub,
//   denominators cancel in the l2-normalizations).
//   sim = (1/(an*30)) * sum_e (sum_p l2n(X[p,:]@att)[e]) * (sum_a l2n(X[:,a]'@patch)[e])
// ---------------------------------------------------------------------------
__global__ __launch_bounds__(256) void pair_kernel(
    const float* __restrict__ patch, const float* __restrict__ att,
    const float* __restrict__ invp, const float* __restrict__ inva,
    const int* __restrict__ att_nums, float* __restrict__ out_sim)
{
    __shared__ float at_s[NA * E_DIM];          // att rows; later reused for ap rows
    __shared__ float ps_s[PC * PS_STRIDE];      // patch chunk; later aa rows
    __shared__ float X_s[PC * XS_STRIDE];       // exp-score chunk
    __shared__ float red_s[64];
    __shared__ float invA_s[32];

    const int v = blockIdx.x, t = blockIdx.y;
    const int tid = threadIdx.x;
    const int Av = att_nums[t];                 // 1..30, wave-uniform

    // load att rows (a < Av) and att inverse norms
    for (int a = 0; a < Av; ++a)
        at_s[a * E_DIM + tid] = att[(t * NA + a) * E_DIM + tid];
    if (tid < 30) invA_s[tid] = inva[t * NA + tid];
    __syncthreads();

    // per-thread column of att (thread == e)
    float at_col[30];
    #pragma unroll
    for (int a = 0; a < 30; ++a) at_col[a] = (a < Av) ? at_s[a * E_DIM + tid] : 0.f;

    float acc_ap[30];
    #pragma unroll
    for (int a = 0; a < 30; ++a) acc_ap[a] = 0.f;
    float sa_reg = 0.f;

    const int pl = tid & 15;     // p within chunk (score phase)
    const int ag = tid >> 4;     // a-group (score phase): a0=ag, a1=ag+16

    for (int c = 0; c < NP / PC; ++c) {
        __syncthreads();  // protect ps_s reuse from previous chunk
        // stage patch chunk (raw)
        #pragma unroll
        for (int i = 0; i < PC; ++i)
            ps_s[i * PS_STRIDE + tid] = patch[(v * NP + c * PC + i) * E_DIM + tid];
        __syncthreads();

        // ---- score phase: S[p,a] then X = exp(relu(20*S*invp*inva)) ----
        {
            const int a0 = ag, a1 = ag + 16;
            const float invp_p = invp[v * NP + c * PC + pl];
            const float* psp = &ps_s[pl * PS_STRIDE];
            const float* a0p = &at_s[a0 * E_DIM];
            const float* a1p = &at_s[a1 * E_DIM];
            float s0a = 0.f, s0b = 0.f, s1a = 0.f, s1b = 0.f;
            #pragma unroll 4
            for (int e = 0; e < E_DIM; e += 8) {
                float4 x0 = *(const float4*)&psp[e];
                float4 x1 = *(const float4*)&psp[e + 4];
                float4 y0 = *(const float4*)&a0p[e];
                float4 y1 = *(const float4*)&a0p[e + 4];
                s0a += x0.x * y0.x + x0.y * y0.y + x0.z * y0.z + x0.w * y0.w;
                s0b += x1.x * y1.x + x1.y * y1.y + x1.z * y1.z + x1.w * y1.w;
                float4 z0 = *(const float4*)&a1p[e];
                float4 z1 = *(const float4*)&a1p[e + 4];
                s1a += x0.x * z0.x + x0.y * z0.y + x0.z * z0.z + x0.w * z0.w;
                s1b += x1.x * z1.x + x1.y * z1.y + x1.z * z1.z + x1.w * z1.w;
            }
            const float s0 = s0a + s0b, s1 = s1a + s1b;
            const float x0v = __expf(fmaxf(s0 * (20.f * invp_p * invA_s[a0]), 0.f));
            const float x1v = __expf(fmaxf(s1 * (20.f * invp_p * invA_s[a1]), 0.f));
            X_s[pl * XS_STRIDE + a0] = (a0 < Av) ? x0v : 0.f;
            X_s[pl * XS_STRIDE + a1] = (a1 < Av) ? x1v : 0.f;
        }
        __syncthreads();

        // ---- fused attend phase (thread == e): ap accum + aa rows ----
        for (int i = 0; i < PC; ++i) {
            const float x = ps_s[i * PS_STRIDE + tid];
            const float* xr = &X_s[i * XS_STRIDE];
            float aa0 = 0.f, aa1 = 0.f;
            #pragma unroll
            for (int q = 0; q < 8; ++q) {
                float4 w = *(const float4*)&xr[q * 4];
                const int ab = 4 * q;
                acc_ap[ab + 0] += w.x * x;  aa0 += w.x * at_col[ab + 0];
                acc_ap[ab + 1] += w.y * x;  aa1 += w.y * at_col[ab + 1];
                if (ab + 2 < 30) { acc_ap[ab + 2] += w.z * x;  aa0 += w.z * at_col[ab + 2]; }
                if (ab + 3 < 30) { acc_ap[ab + 3] += w.w * x;  aa1 += w.w * at_col[ab + 3]; }
            }
            ps_s[i * PS_STRIDE + tid] = aa0 + aa1;   // own slot only: no race
        }
        __syncthreads();

        // ---- row norms of aa (16 teams of 16 lanes) ----
        {
            const int team = tid >> 4, l16 = tid & 15;
            const float* rr = &ps_s[team * PS_STRIDE];
            float ssq = 0.f;
            #pragma unroll
            for (int j = 0; j < 16; ++j) { float vv = rr[l16 + 16 * j]; ssq += vv * vv; }
            #pragma unroll
            for (int off = 8; off >= 1; off >>= 1) ssq += __shfl_xor(ssq, off, 16);
            if (l16 == 0) red_s[team] = 1.f / fmaxf(sqrtf(ssq), 1e-12f);
        }
        __syncthreads();
        #pragma unroll
        for (int i = 0; i < PC; ++i)
            sa_reg += ps_s[i * PS_STRIDE + tid] * red_s[i];
    }

    // ---- ap norms and rank-1 contraction ----
    __syncthreads();
    #pragma unroll
    for (int a = 0; a < 30; ++a)
        if (a < Av) at_s[a * E_DIM + tid] = acc_ap[a];
    __syncthreads();
    {
        const int wid = tid >> 6, lane = tid & 63;
        for (int rr = 0; rr < 8; ++rr) {
            const int a = wid + 4 * rr;
            if (a < Av) {
                float ssq = 0.f;
                #pragma unroll
                for (int j = 0; j < 4; ++j) {
                    float vv = at_s[a * E_DIM + lane + 64 * j];
                    ssq += vv * vv;
                }
                #pragma unroll
                for (int off = 32; off >= 1; off >>= 1) ssq += __shfl_xor(ssq, off, 64);
                if (lane == 0) red_s[32 + a] = 1.f / fmaxf(sqrtf(ssq), 1e-12f);
            }
        }
    }
    __syncthreads();
    float sp_reg = 0.f;
    #pragma unroll
    for (int a = 0; a < 30; ++a)
        if (a < Av) sp_reg += at_s[a * E_DIM + tid] * red_s[32 + a];

    float prod = sa_reg * sp_reg;
    #pragma unroll
    for (int off = 32; off >= 1; off >>= 1) prod += __shfl_xor(prod, off, 64);
    const int wid = tid >> 6, lane = tid & 63;
    if (lane == 0) red_s[wid] = prod;   // slots 0..3 (dead now)
    __syncthreads();
    if (tid == 0) {
        float tot = red_s[0] + red_s[1] + red_s[2] + red_s[3];
        out_sim[t * NB + v] = tot / ((float)Av * 30.0f);
    }
}

// ---------------------------------------------------------------------------
extern "C" void kernel_launch(void* const* d_in, const int* in_sizes, int n_in,
                              void* d_out, int out_size, void* d_ws, size_t ws_size,
                              hipStream_t stream)
{
    const float* vf = (const float*)d_in[0];   // [32,193,768]
    const float* tf = (const float*)d_in[1];   // [32,31,768]
    // d_in[2] = mask (unused; att_nums carries the same info)
    const int*   an = (const int*)d_in[3];     // [32]
    const float* Wv = (const float*)d_in[4];
    const float* bv = (const float*)d_in[5];
    const float* Wt = (const float*)d_in[6];
    const float* bt = (const float*)d_in[7];
    const float* Wp = (const float*)d_in[8];
    const float* bp = (const float*)d_in[9];
    const float* Wa = (const float*)d_in[10];
    const float* ba = (const float*)d_in[11];

    float* out = (float*)d_out;
    float* out_vis = out;             // [32,256]
    float* out_txt = out + 8192;      // [32,256]
    float* out_pm  = out + 16384;     // [32,256]
    float* out_am  = out + 24576;     // [32,256]
    float* out_sim = out + 32768;     // [32,32]

    float* ws    = (float*)d_ws;
    float* patch = ws;                          // 32*192*256 = 1,572,864
    float* att   = ws + 1572864;                // 32*30*256  =   245,760
    float* invp  = ws + 1572864 + 245760;       // 6144
    float* inva  = ws + 1572864 + 245760 + 6144;// 960

    proj_kernel<<<224, 256, 0, stream>>>(vf, tf, Wv, bv, Wt, bt, Wp, bp, Wa, ba,
                                         out_vis, out_txt, patch, att);
    norm_kernel<<<(NB * NP + NB * NA) / 4, 256, 0, stream>>>(patch, att, invp, inva);
    mean_kernel<<<64, 256, 0, stream>>>(patch, att, an, out_pm, out_am);
    pair_kernel<<<dim3(NB, NB), 256, 0, stream>>>(patch, att, invp, inva, an, out_sim);
}

// Round 2
// 231.729 us; speedup vs baseline: 4.0310x; 4.0310x over previous
//
#include <hip/hip_runtime.h>
#include <math.h>

#define D_IN 768
#define E_DIM 256
#define NB 32
#define NP 192
#define NA 30

typedef __attribute__((ext_vector_type(8))) __bf16 bf16x8;
typedef __attribute__((ext_vector_type(4))) float f32x4;

// ---------------------------------------------------------------------------
// Projection GEMM (unchanged from R1, known-good): Y[m][e] = X[row(m)]·W[e] + b
// ---------------------------------------------------------------------------
__global__ __launch_bounds__(256) void proj_kernel(
    const float* __restrict__ vf, const float* __restrict__ tf,
    const float* __restrict__ Wv, const float* __restrict__ bv,
    const float* __restrict__ Wt, const float* __restrict__ bt,
    const float* __restrict__ Wp, const float* __restrict__ bp,
    const float* __restrict__ Wa, const float* __restrict__ ba,
    float* __restrict__ out_vis, float* __restrict__ out_txt,
    float* __restrict__ patch, float* __restrict__ att)
{
    __shared__ float Xs[32 * 36];
    __shared__ float Ws[32 * 260];

    const int bid = blockIdx.x;
    const float *X, *W, *bias;
    float* Y;
    int m0, RPB, TPB, TOFF;
    if (bid < 192)       { X = vf; W = Wp; bias = bp; Y = patch;   m0 = bid * 32;         RPB = 192; TPB = 193; TOFF = 1; }
    else if (bid < 222)  { X = tf; W = Wa; bias = ba; Y = att;     m0 = (bid - 192) * 32; RPB = 30;  TPB = 31;  TOFF = 1; }
    else if (bid == 222) { X = vf; W = Wv; bias = bv; Y = out_vis; m0 = 0;                RPB = 1;   TPB = 193; TOFF = 0; }
    else                 { X = tf; W = Wt; bias = bt; Y = out_txt; m0 = 0;                RPB = 1;   TPB = 31;  TOFF = 0; }

    const int tid = threadIdx.x;
    const int et  = tid & 63;
    const int mg  = tid >> 6;
    const int e0  = et * 4;
    const int m0l = mg * 8;
    const int k4 = tid & 7;
    const int sm = tid >> 3;

    const int r = m0 + sm;
    const int batch = r / RPB;
    const int idx = r - batch * RPB;
    const float* xrow = X + (batch * TPB + TOFF + idx) * D_IN;

    float acc[8][4];
    #pragma unroll
    for (int i = 0; i < 8; ++i)
        #pragma unroll
        for (int c = 0; c < 4; ++c) acc[i][c] = 0.f;

    for (int kk = 0; kk < D_IN; kk += 32) {
        {
            float4 xv = *(const float4*)&xrow[kk + k4 * 4];
            Xs[(k4 * 4 + 0) * 36 + sm] = xv.x;
            Xs[(k4 * 4 + 1) * 36 + sm] = xv.y;
            Xs[(k4 * 4 + 2) * 36 + sm] = xv.z;
            Xs[(k4 * 4 + 3) * 36 + sm] = xv.w;
        }
        #pragma unroll
        for (int j = 0; j < 8; ++j) {
            const int e = sm + 32 * j;
            float4 wv = *(const float4*)&W[e * D_IN + kk + k4 * 4];
            Ws[(k4 * 4 + 0) * 260 + e] = wv.x;
            Ws[(k4 * 4 + 1) * 260 + e] = wv.y;
            Ws[(k4 * 4 + 2) * 260 + e] = wv.z;
            Ws[(k4 * 4 + 3) * 260 + e] = wv.w;
        }
        __syncthreads();
        #pragma unroll
        for (int k = 0; k < 32; ++k) {
            float4 w  = *(const float4*)&Ws[k * 260 + e0];
            float4 x0 = *(const float4*)&Xs[k * 36 + m0l];
            float4 x1 = *(const float4*)&Xs[k * 36 + m0l + 4];
            float xs[8] = {x0.x, x0.y, x0.z, x0.w, x1.x, x1.y, x1.z, x1.w};
            #pragma unroll
            for (int mi = 0; mi < 8; ++mi) {
                acc[mi][0] += xs[mi] * w.x;
                acc[mi][1] += xs[mi] * w.y;
                acc[mi][2] += xs[mi] * w.z;
                acc[mi][3] += xs[mi] * w.w;
            }
        }
        __syncthreads();
    }

    float4 bvv = *(const float4*)&bias[e0];
    #pragma unroll
    for (int mi = 0; mi < 8; ++mi) {
        float4 st;
        st.x = acc[mi][0] + bvv.x;
        st.y = acc[mi][1] + bvv.y;
        st.z = acc[mi][2] + bvv.z;
        st.w = acc[mi][3] + bvv.w;
        *(float4*)&Y[(m0 + m0l + mi) * E_DIM + e0] = st;
    }
}

// ---------------------------------------------------------------------------
// Row inverse-norms (unchanged)
// ---------------------------------------------------------------------------
__global__ __launch_bounds__(256) void norm_kernel(
    const float* __restrict__ patch, const float* __restrict__ att,
    float* __restrict__ invp, float* __restrict__ inva)
{
    const int row  = blockIdx.x * 4 + (threadIdx.x >> 6);
    const int lane = threadIdx.x & 63;
    const float* src;
    float* dst;
    if (row < NB * NP) { src = patch + row * E_DIM;            dst = invp + row; }
    else               { src = att + (row - NB * NP) * E_DIM;  dst = inva + (row - NB * NP); }

    float4 xv = *(const float4*)&src[lane * 4];
    float ssq = xv.x * xv.x + xv.y * xv.y + xv.z * xv.z + xv.w * xv.w;
    #pragma unroll
    for (int off = 32; off >= 1; off >>= 1) ssq += __shfl_xor(ssq, off, 64);
    if (lane == 0) *dst = 1.f / fmaxf(sqrtf(ssq), 1e-12f);
}

// ---------------------------------------------------------------------------
// Means (unchanged)
// ---------------------------------------------------------------------------
__global__ __launch_bounds__(256) void mean_kernel(
    const float* __restrict__ patch, const float* __restrict__ att,
    const int* __restrict__ att_nums,
    float* __restrict__ out_pm, float* __restrict__ out_am)
{
    const int tid = threadIdx.x;
    if (blockIdx.x < 32) {
        const int v = blockIdx.x;
        float s = 0.f;
        for (int p = 0; p < NP; ++p) s += patch[(v * NP + p) * E_DIM + tid];
        out_pm[v * E_DIM + tid] = s * (1.f / (float)NP);
    } else {
        const int t = blockIdx.x - 32;
        float s = 0.f;
        #pragma unroll
        for (int a = 0; a < NA; ++a) s += att[(t * NA + a) * E_DIM + tid];
        out_am[t * E_DIM + tid] = s / (float)att_nums[t];
    }
}

// ---------------------------------------------------------------------------
// MFMA pair kernel: one block per (v,t).
// Per 32-row patch chunk: S=cos via mfma(pn,an) -> X=exp(relu(20S)) (bf16, both
// X and X^T A-frag layouts in LDS) -> aa = X·attB, ap += X^T·patchB via mfma.
// Row-norm + rank-1 contraction epilogue (fp32).
// Fragment layouts (16x16x32 bf16, measured m89/m91):
//   A/B row-frag: lane l holds row (l&15), k = (l>>4)*8 + j  -> store elem
//   (row,k) at ((l)*8 + j) within a 16x32 tile => wave load = 64x16B contiguous.
//   C/D: col = lane&15, row = (lane>>4)*4 + reg.
// ---------------------------------------------------------------------------
__global__ __launch_bounds__(256) void pair_mfma_kernel(
    const float* __restrict__ patch, const float* __restrict__ att,
    const float* __restrict__ invp, const float* __restrict__ inva,
    const int* __restrict__ att_nums, float* __restrict__ out_sim)
{
    __shared__ __align__(16) __bf16 an_s[8192];   // l2norm(att), row-frag: [at(2)][kp(8)][lane(64)][8]
    __shared__ __align__(16) __bf16 attB_s[8192]; // raw att, B-frag: [nt(16)][lane(64)][8] (k=a)
    __shared__ __align__(16) __bf16 pn_s[8192];   // l2norm(patch chunk), row-frag
    __shared__ __align__(16) __bf16 pB_s[8192];   // raw patch chunk, B-frag (k=p)
    __shared__ __align__(16) __bf16 Xa_s[1024];   // X,  A-frag rows=p, k=a
    __shared__ __align__(16) __bf16 XaT_s[1024];  // X^T, A-frag rows=a, k=p
    __shared__ float red_s[128];
    __shared__ float invn_s[32];
    __shared__ float wred_s[4];

    const int v = blockIdx.x, t = blockIdx.y;
    const int tid = threadIdx.x;
    const int w = tid >> 6, l = tid & 63, q = l >> 4, n15 = l & 15;
    const int Av = att_nums[t];

    // ---- stage att once: normalized row-frag + raw B-frag (zero rows >=30) ----
    {
        const int a = tid >> 3, oct = tid & 7;
        const float ia = (a < 30) ? inva[t * 30 + a] : 0.f;
        const float* arow = att + (t * 30 + (a < 30 ? a : 0)) * E_DIM;
        #pragma unroll
        for (int cc = 0; cc < 4; ++cc) {
            const int e0 = oct * 8 + 64 * cc;
            float xv[8];
            if (a < 30) {
                float4 f0 = *(const float4*)&arow[e0];
                float4 f1 = *(const float4*)&arow[e0 + 4];
                xv[0] = f0.x; xv[1] = f0.y; xv[2] = f0.z; xv[3] = f0.w;
                xv[4] = f1.x; xv[5] = f1.y; xv[6] = f1.z; xv[7] = f1.w;
            } else {
                #pragma unroll
                for (int i = 0; i < 8; ++i) xv[i] = 0.f;
            }
            bf16x8 vn;
            #pragma unroll
            for (int i = 0; i < 8; ++i) vn[i] = (__bf16)(xv[i] * ia);
            *(bf16x8*)&an_s[(((a >> 4) * 8 + (e0 >> 5)) * 64 + (a & 15) + 16 * ((e0 >> 3) & 3)) * 8] = vn;
            const int nt = e0 >> 4, nb = e0 & 15;
            #pragma unroll
            for (int i = 0; i < 8; ++i)
                attB_s[nt * 512 + ((nb + i) + 16 * (a >> 3)) * 8 + (a & 7)] = (__bf16)xv[i];
        }
    }

    f32x4 apacc[2][4];
    #pragma unroll
    for (int m = 0; m < 2; ++m)
        #pragma unroll
        for (int n = 0; n < 4; ++n) { f32x4 z = {0.f, 0.f, 0.f, 0.f}; apacc[m][n] = z; }
    float sa_acc[4] = {0.f, 0.f, 0.f, 0.f};

    for (int c = 0; c < 6; ++c) {
        __syncthreads();  // protect pn/pB/Xa/XaT from previous chunk readers
        // ---- stage patch chunk: normalized row-frag + raw B-frag ----
        {
            const int pc = tid >> 3, oct = tid & 7;
            const int prow = v * NP + c * 32 + pc;
            const float ipv = invp[prow];
            const float* srow = patch + prow * E_DIM;
            #pragma unroll
            for (int cc = 0; cc < 4; ++cc) {
                const int e0 = oct * 8 + 64 * cc;
                float4 f0 = *(const float4*)&srow[e0];
                float4 f1 = *(const float4*)&srow[e0 + 4];
                float xv[8] = {f0.x, f0.y, f0.z, f0.w, f1.x, f1.y, f1.z, f1.w};
                bf16x8 vn;
                #pragma unroll
                for (int i = 0; i < 8; ++i) vn[i] = (__bf16)(xv[i] * ipv);
                *(bf16x8*)&pn_s[(((pc >> 4) * 8 + (e0 >> 5)) * 64 + (pc & 15) + 16 * ((e0 >> 3) & 3)) * 8] = vn;
                const int nt = e0 >> 4, nb = e0 & 15;
                #pragma unroll
                for (int i = 0; i < 8; ++i)
                    pB_s[nt * 512 + ((nb + i) + 16 * (pc >> 3)) * 8 + (pc & 7)] = (__bf16)xv[i];
            }
        }
        __syncthreads();

        // ---- score GEMM: wave handles (mt = w>>1, at = w&1); S = cos ----
        {
            const int mt = w >> 1, at = w & 1;
            f32x4 sacc = {0.f, 0.f, 0.f, 0.f};
            #pragma unroll
            for (int kp = 0; kp < 8; ++kp) {
                bf16x8 af = *(const bf16x8*)&pn_s[((mt * 8 + kp) * 64 + l) * 8];
                bf16x8 bf = *(const bf16x8*)&an_s[((at * 8 + kp) * 64 + l) * 8];
                sacc = __builtin_amdgcn_mfma_f32_16x16x32_bf16(af, bf, sacc, 0, 0, 0);
            }
            const int a = at * 16 + n15;
            #pragma unroll
            for (int r = 0; r < 4; ++r) {
                const int pcl = q * 4 + r;          // row within 16-tile
                const int pcc = mt * 16 + pcl;      // row within chunk (0..31)
                float xvv = (a < Av) ? __expf(fmaxf(20.f * sacc[r], 0.f)) : 0.f;
                __bf16 h = (__bf16)xvv;
                Xa_s[mt * 512 + (pcl + 16 * (a >> 3)) * 8 + (a & 7)] = h;
                XaT_s[at * 512 + (n15 + 16 * (pcc >> 3)) * 8 + (pcc & 7)] = h;
            }
        }
        __syncthreads();

        // ---- aa = X·att (fresh per chunk), ap += X^T·patch (accumulated) ----
        f32x4 aacc[2][4];
        {
            bf16x8 xa0 = *(const bf16x8*)&Xa_s[l * 8];
            bf16x8 xa1 = *(const bf16x8*)&Xa_s[512 + l * 8];
            bf16x8 xt0 = *(const bf16x8*)&XaT_s[l * 8];
            bf16x8 xt1 = *(const bf16x8*)&XaT_s[512 + l * 8];
            #pragma unroll
            for (int n = 0; n < 4; ++n) {
                bf16x8 ab = *(const bf16x8*)&attB_s[(w * 4 + n) * 512 + l * 8];
                f32x4 z = {0.f, 0.f, 0.f, 0.f};
                aacc[0][n] = __builtin_amdgcn_mfma_f32_16x16x32_bf16(xa0, ab, z, 0, 0, 0);
                aacc[1][n] = __builtin_amdgcn_mfma_f32_16x16x32_bf16(xa1, ab, z, 0, 0, 0);
                bf16x8 pb = *(const bf16x8*)&pB_s[(w * 4 + n) * 512 + l * 8];
                apacc[0][n] = __builtin_amdgcn_mfma_f32_16x16x32_bf16(xt0, pb, apacc[0][n], 0, 0, 0);
                apacc[1][n] = __builtin_amdgcn_mfma_f32_16x16x32_bf16(xt1, pb, apacc[1][n], 0, 0, 0);
            }
        }

        // ---- aa row norms (row = mt2*16 + q*4 + r; e split across waves) ----
        #pragma unroll
        for (int mt2 = 0; mt2 < 2; ++mt2)
            #pragma unroll
            for (int r = 0; r < 4; ++r) {
                float ssq = 0.f;
                #pragma unroll
                for (int n = 0; n < 4; ++n) { float vv = aacc[mt2][n][r]; ssq += vv * vv; }
                ssq += __shfl_xor(ssq, 1, 64);
                ssq += __shfl_xor(ssq, 2, 64);
                ssq += __shfl_xor(ssq, 4, 64);
                ssq += __shfl_xor(ssq, 8, 64);
                if (n15 == 0) red_s[(mt2 * 16 + q * 4 + r) * 4 + w] = ssq;
            }
        __syncthreads();
        if (tid < 32) {
            float s = red_s[tid * 4] + red_s[tid * 4 + 1] + red_s[tid * 4 + 2] + red_s[tid * 4 + 3];
            invn_s[tid] = 1.f / fmaxf(sqrtf(s), 1e-12f);
        }
        __syncthreads();
        #pragma unroll
        for (int mt2 = 0; mt2 < 2; ++mt2)
            #pragma unroll
            for (int r = 0; r < 4; ++r) {
                const float inr = invn_s[mt2 * 16 + q * 4 + r];
                #pragma unroll
                for (int n = 0; n < 4; ++n) sa_acc[n] += aacc[mt2][n][r] * inr;
            }
    }

    // ---- ap row norms (rows = a; zero rows give 0 * 1/eps = 0) ----
    #pragma unroll
    for (int mt2 = 0; mt2 < 2; ++mt2)
        #pragma unroll
        for (int r = 0; r < 4; ++r) {
            float ssq = 0.f;
            #pragma unroll
            for (int n = 0; n < 4; ++n) { float vv = apacc[mt2][n][r]; ssq += vv * vv; }
            ssq += __shfl_xor(ssq, 1, 64);
            ssq += __shfl_xor(ssq, 2, 64);
            ssq += __shfl_xor(ssq, 4, 64);
            ssq += __shfl_xor(ssq, 8, 64);
            if (n15 == 0) red_s[(mt2 * 16 + q * 4 + r) * 4 + w] = ssq;
        }
    __syncthreads();
    if (tid < 32) {
        float s = red_s[tid * 4] + red_s[tid * 4 + 1] + red_s[tid * 4 + 2] + red_s[tid * 4 + 3];
        invn_s[tid] = 1.f / fmaxf(sqrtf(s), 1e-12f);
    }
    __syncthreads();

    // ---- rank-1 contraction: sim = sum_e sa[e]*sp[e] / (Av*30) ----
    float prod = 0.f;
    #pragma unroll
    for (int n = 0; n < 4; ++n) {
        float sp = 0.f;
        #pragma unroll
        for (int mt2 = 0; mt2 < 2; ++mt2)
            #pragma unroll
            for (int r = 0; r < 4; ++r)
                sp += apacc[mt2][n][r] * invn_s[mt2 * 16 + q * 4 + r];
        float saf = sa_acc[n];
        saf += __shfl_xor(saf, 16, 64);
        saf += __shfl_xor(saf, 32, 64);   // full sa[e], replicated over q groups
        float spf = sp;
        spf += __shfl_xor(spf, 16, 64);
        spf += __shfl_xor(spf, 32, 64);
        prod += saf * spf;
    }
    prod += __shfl_xor(prod, 1, 64);
    prod += __shfl_xor(prod, 2, 64);
    prod += __shfl_xor(prod, 4, 64);
    prod += __shfl_xor(prod, 8, 64);
    prod += __shfl_xor(prod, 16, 64);
    prod += __shfl_xor(prod, 32, 64);     // sums 16 e's x 4 q-copies -> *0.25
    if (l == 0) wred_s[w] = prod;
    __syncthreads();
    if (tid == 0)
        out_sim[t * NB + v] = (wred_s[0] + wred_s[1] + wred_s[2] + wred_s[3]) * 0.25f
                              / ((float)Av * 30.f);
}

// ---------------------------------------------------------------------------
extern "C" void kernel_launch(void* const* d_in, const int* in_sizes, int n_in,
                              void* d_out, int out_size, void* d_ws, size_t ws_size,
                              hipStream_t stream)
{
    const float* vf = (const float*)d_in[0];
    const float* tf = (const float*)d_in[1];
    const int*   an = (const int*)d_in[3];
    const float* Wv = (const float*)d_in[4];
    const float* bv = (const float*)d_in[5];
    const float* Wt = (const float*)d_in[6];
    const float* bt = (const float*)d_in[7];
    const float* Wp = (const float*)d_in[8];
    const float* bp = (const float*)d_in[9];
    const float* Wa = (const float*)d_in[10];
    const float* ba = (const float*)d_in[11];

    float* out = (float*)d_out;
    float* out_vis = out;
    float* out_txt = out + 8192;
    float* out_pm  = out + 16384;
    float* out_am  = out + 24576;
    float* out_sim = out + 32768;

    float* ws    = (float*)d_ws;
    float* patch = ws;
    float* att   = ws + 1572864;
    float* invp  = ws + 1572864 + 245760;
    float* inva  = ws + 1572864 + 245760 + 6144;

    proj_kernel<<<224, 256, 0, stream>>>(vf, tf, Wv, bv, Wt, bt, Wp, bp, Wa, ba,
                                         out_vis, out_txt, patch, att);
    norm_kernel<<<(NB * NP + NB * NA) / 4, 256, 0, stream>>>(patch, att, invp, inva);
    mean_kernel<<<64, 256, 0, stream>>>(patch, att, an, out_pm, out_am);
    pair_mfma_kernel<<<dim3(NB, NB), 256, 0, stream>>>(patch, att, invp, inva, an, out_sim);
}

// Round 3
// 163.371 us; speedup vs baseline: 5.7176x; 1.4184x over previous
//
#include <hip/hip_runtime.h>
#include <math.h>

#define D_IN 768
#define E_DIM 256
#define NB 32
#define NP 192
#define NA 30

typedef __attribute__((ext_vector_type(8))) __bf16 bf16x8;
typedef __attribute__((ext_vector_type(4))) float f32x4;

// ---------------------------------------------------------------------------
// Fused projection kernel (MFMA bf16) + norm/mean/fragment-pack epilogue.
// grid = 226 blocks:
//   [0,192)   : patch blocks, block = (v = bid/6, chunk c = bid%6), 32 rows
//   [192,224) : att blocks, one per t, 30 rows (padded to 32)
//   224       : visual_embed (32 rows), 225: textual_embed (32 rows)
// Each block: Y[32x256] = X[32x768] * W[256x768]^T + b via 16x16x32 bf16 MFMA.
// Patch/att blocks then compute row inv-norms, means, and write bf16
// fragment-layout tensors consumed by pair_mfma_kernel:
//   pn_frag[v][c] : l2norm(patch) A-row-frag  [mt2][koct8][lane64][8]
//   pB_frag[v][c] : raw patch B-frag (k=p)    [nt16][lane64][8]
//   an_frag[t]    : l2norm(att) row-frag      [at2][koct8][lane64][8]
//   attT_frag[t]  : raw att B-frag (k=a)      [nt16][lane64][8]
// ---------------------------------------------------------------------------
__global__ __launch_bounds__(256) void proj_fused_kernel(
    const float* __restrict__ vf, const float* __restrict__ tf,
    const float* __restrict__ Wv, const float* __restrict__ bv,
    const float* __restrict__ Wt, const float* __restrict__ bt,
    const float* __restrict__ Wp, const float* __restrict__ bp,
    const float* __restrict__ Wa, const float* __restrict__ ba,
    const int* __restrict__ att_nums,
    float* __restrict__ out_vis, float* __restrict__ out_txt,
    float* __restrict__ out_pm, float* __restrict__ out_am,
    __bf16* __restrict__ pn_frag, __bf16* __restrict__ pB_frag,
    __bf16* __restrict__ an_frag, __bf16* __restrict__ attT_frag)
{
    // As: 2048 bf16 (4 KB) | Bs: 16384 bf16 (32 KB) | epilogue aliases LDSf
    __shared__ __align__(16) unsigned char smem[36864];
    __bf16* As = (__bf16*)smem;
    __bf16* Bs = (__bf16*)(smem + 4096);
    float*  LDSf = (float*)smem;          // 32 x 260 fp32 = 33280 B (aliased)
    __shared__ float invn_s[32];

    const int bid = blockIdx.x;
    const int tid = threadIdx.x;
    const int w = tid >> 6, l = tid & 63, q = l >> 4, n15 = l & 15;

    int role;  // 0 patch, 1 att, 2 vis, 3 txt
    const float *W, *bias;
    if (bid < 192)       { role = 0; W = Wp; bias = bp; }
    else if (bid < 224)  { role = 1; W = Wa; bias = ba; }
    else if (bid == 224) { role = 2; W = Wv; bias = bv; }
    else                 { role = 3; W = Wt; bias = bt; }

    // A staging: thread owns row rl = tid>>3, k-oct = tid&7 (of 64-k chunk)
    const int rl = tid >> 3, oct = tid & 7;
    const float* arow;
    if (role == 0) {
        const int r = bid * 32 + rl;
        const int b = r / NP, idx = r - b * NP;
        arow = vf + (size_t)(b * 193 + 1 + idx) * D_IN;
    } else if (role == 1) {
        const int t = bid - 192;
        const int rr = (rl < NA) ? rl : 0;           // pad rows duplicate row 0
        arow = tf + (size_t)(t * 31 + 1 + rr) * D_IN;
    } else if (role == 2) {
        arow = vf + (size_t)rl * 193 * D_IN;         // token 0 of batch rl
    } else {
        arow = tf + (size_t)rl * 31 * D_IN;
    }
    const float* wrow = W + (size_t)tid * D_IN;      // thread owns e-row = tid
    const int et = tid >> 4, elo = tid & 15;

    f32x4 acc[2][4];
    #pragma unroll
    for (int m = 0; m < 2; ++m)
        #pragma unroll
        for (int n = 0; n < 4; ++n) { f32x4 z = {0.f,0.f,0.f,0.f}; acc[m][n] = z; }

    for (int kk = 0; kk < D_IN; kk += 64) {
        __syncthreads();
        // ---- A tile -> A-row-frag layout [mt2][koct2][lane][8] ----
        {
            float4 f0 = *(const float4*)&arow[kk + oct * 8];
            float4 f1 = *(const float4*)&arow[kk + oct * 8 + 4];
            bf16x8 vv;
            vv[0]=(__bf16)f0.x; vv[1]=(__bf16)f0.y; vv[2]=(__bf16)f0.z; vv[3]=(__bf16)f0.w;
            vv[4]=(__bf16)f1.x; vv[5]=(__bf16)f1.y; vv[6]=(__bf16)f1.z; vv[7]=(__bf16)f1.w;
            const int mt = rl >> 4, koct = oct >> 2;
            *(bf16x8*)&As[(((mt * 2 + koct) * 64) + (rl & 15) + 16 * (oct & 3)) * 8] = vv;
        }
        // ---- B tile (W rows) -> B-row-frag layout [koct2][et16][lane][8] ----
        #pragma unroll
        for (int o = 0; o < 8; ++o) {
            float4 f0 = *(const float4*)&wrow[kk + o * 8];
            float4 f1 = *(const float4*)&wrow[kk + o * 8 + 4];
            bf16x8 vv;
            vv[0]=(__bf16)f0.x; vv[1]=(__bf16)f0.y; vv[2]=(__bf16)f0.z; vv[3]=(__bf16)f0.w;
            vv[4]=(__bf16)f1.x; vv[5]=(__bf16)f1.y; vv[6]=(__bf16)f1.z; vv[7]=(__bf16)f1.w;
            *(bf16x8*)&Bs[(((o >> 2) * 16 + et) * 64 + elo + 16 * (o & 3)) * 8] = vv;
        }
        __syncthreads();
        // ---- MFMA: wave w covers e-tiles w*4..w*4+3, both m-tiles ----
        #pragma unroll
        for (int kq = 0; kq < 2; ++kq) {
            bf16x8 a0 = *(const bf16x8*)&As[((0 * 2 + kq) * 64 + l) * 8];
            bf16x8 a1 = *(const bf16x8*)&As[((1 * 2 + kq) * 64 + l) * 8];
            #pragma unroll
            for (int nt = 0; nt < 4; ++nt) {
                bf16x8 bf_ = *(const bf16x8*)&Bs[((kq * 16 + (w * 4 + nt)) * 64 + l) * 8];
                acc[0][nt] = __builtin_amdgcn_mfma_f32_16x16x32_bf16(a0, bf_, acc[0][nt], 0, 0, 0);
                acc[1][nt] = __builtin_amdgcn_mfma_f32_16x16x32_bf16(a1, bf_, acc[1][nt], 0, 0, 0);
            }
        }
    }
    __syncthreads();   // done with As/Bs; LDSf aliases them below

    // ---- embeds: direct store (C-layout: row = mt*16+q*4+r, col = e) ----
    if (role >= 2) {
        float* outp = (role == 2) ? out_vis : out_txt;
        #pragma unroll
        for (int mt = 0; mt < 2; ++mt)
            #pragma unroll
            for (int nt = 0; nt < 4; ++nt) {
                const int col = (w * 4 + nt) * 16 + n15;
                const float b = bias[col];
                #pragma unroll
                for (int r = 0; r < 4; ++r) {
                    const int row = mt * 16 + q * 4 + r;
                    outp[row * E_DIM + col] = acc[mt][nt][r] + b;
                }
            }
        return;
    }

    // ---- spill acc (+bias) to LDSf[32][260] ----
    #pragma unroll
    for (int mt = 0; mt < 2; ++mt)
        #pragma unroll
        for (int nt = 0; nt < 4; ++nt) {
            const int col = (w * 4 + nt) * 16 + n15;
            const float b = bias[col];
            #pragma unroll
            for (int r = 0; r < 4; ++r)
                LDSf[(mt * 16 + q * 4 + r) * 260 + col] = acc[mt][nt][r] + b;
        }
    __syncthreads();

    if (role == 0) {
        const int v = bid / 6, c = bid - 6 * v;
        // row inv-norms: 8 threads per row
        {
            const int row = tid >> 3, seg = tid & 7;
            const float* rr = &LDSf[row * 260 + seg * 32];
            float ssq = 0.f;
            #pragma unroll
            for (int j = 0; j < 32; ++j) ssq += rr[j] * rr[j];
            ssq += __shfl_xor(ssq, 1, 64);
            ssq += __shfl_xor(ssq, 2, 64);
            ssq += __shfl_xor(ssq, 4, 64);
            if (seg == 0) invn_s[row] = 1.f / fmaxf(sqrtf(ssq), 1e-12f);
        }
        // patch_mean partial (thread = e)
        {
            float s = 0.f;
            #pragma unroll
            for (int r = 0; r < 32; ++r) s += LDSf[r * 260 + tid];
            atomicAdd(&out_pm[v * E_DIM + tid], s * (1.f / 192.f));
        }
        __syncthreads();
        // pn_frag (normalized, A-row-frag) — contiguous 16B stores
        __bf16* dstn = pn_frag + (size_t)(v * 6 + c) * 8192;
        #pragma unroll
        for (int i = 0; i < 4; ++i) {
            const int slot = tid + 256 * i;
            const int mt = slot >> 9, koct = (slot >> 6) & 7, lane = slot & 63;
            const int prl = mt * 16 + (lane & 15);
            const int e0 = koct * 32 + (lane >> 4) * 8;
            const float inr = invn_s[prl];
            const float* src = &LDSf[prl * 260 + e0];
            bf16x8 vv;
            #pragma unroll
            for (int j = 0; j < 8; ++j) vv[j] = (__bf16)(src[j] * inr);
            *(bf16x8*)&dstn[slot * 8] = vv;
        }
        // pB_frag (raw, B-frag k=p)
        __bf16* dstb = pB_frag + (size_t)(v * 6 + c) * 8192;
        #pragma unroll
        for (int i = 0; i < 4; ++i) {
            const int slot = tid + 256 * i;
            const int nt = slot >> 6, lane = slot & 63;
            const int e = nt * 16 + (lane & 15);
            const int p0 = (lane >> 4) * 8;
            bf16x8 vv;
            #pragma unroll
            for (int j = 0; j < 8; ++j) vv[j] = (__bf16)LDSf[(p0 + j) * 260 + e];
            *(bf16x8*)&dstb[slot * 8] = vv;
        }
    } else {
        const int t = bid - 192;
        const int Av = att_nums[t];
        {
            const int row = tid >> 3, seg = tid & 7;
            const float* rr = &LDSf[row * 260 + seg * 32];
            float ssq = 0.f;
            #pragma unroll
            for (int j = 0; j < 32; ++j) ssq += rr[j] * rr[j];
            ssq += __shfl_xor(ssq, 1, 64);
            ssq += __shfl_xor(ssq, 2, 64);
            ssq += __shfl_xor(ssq, 4, 64);
            if (seg == 0) invn_s[row] = (row < NA) ? 1.f / fmaxf(sqrtf(ssq), 1e-12f) : 0.f;
        }
        {
            float s = 0.f;
            #pragma unroll
            for (int r = 0; r < NA; ++r) s += LDSf[r * 260 + tid];
            out_am[t * E_DIM + tid] = s / (float)Av;
        }
        __syncthreads();
        // an_frag (normalized row-frag; rows >=30 zero)
        __bf16* dstn = an_frag + (size_t)t * 8192;
        #pragma unroll
        for (int i = 0; i < 4; ++i) {
            const int slot = tid + 256 * i;
            const int at = slot >> 9, koct = (slot >> 6) & 7, lane = slot & 63;
            const int a = at * 16 + (lane & 15);
            const int e0 = koct * 32 + (lane >> 4) * 8;
            const float inr = (a < NA) ? invn_s[a] : 0.f;
            const float* src = &LDSf[a * 260 + e0];
            bf16x8 vv;
            #pragma unroll
            for (int j = 0; j < 8; ++j) vv[j] = (__bf16)(src[j] * inr);
            *(bf16x8*)&dstn[slot * 8] = vv;
        }
        // attT_frag (raw, B-frag k=a; a>=30 zero)
        __bf16* dstb = attT_frag + (size_t)t * 8192;
        #pragma unroll
        for (int i = 0; i < 4; ++i) {
            const int slot = tid + 256 * i;
            const int nt = slot >> 6, lane = slot & 63;
            const int e = nt * 16 + (lane & 15);
            const int a0 = (lane >> 4) * 8;
            bf16x8 vv;
            #pragma unroll
            for (int j = 0; j < 8; ++j)
                vv[j] = (a0 + j < NA) ? (__bf16)LDSf[(a0 + j) * 260 + e] : (__bf16)0.f;
            *(bf16x8*)&dstb[slot * 8] = vv;
        }
    }
}

// ---------------------------------------------------------------------------
// MFMA pair kernel: one block per (v,t). All staging = contiguous 16B copies.
// ---------------------------------------------------------------------------
__global__ __launch_bounds__(256) void pair_mfma_kernel(
    const __bf16* __restrict__ pn_frag, const __bf16* __restrict__ pB_frag,
    const __bf16* __restrict__ an_frag, const __bf16* __restrict__ attT_frag,
    const int* __restrict__ att_nums, float* __restrict__ out_sim)
{
    __shared__ __align__(16) __bf16 an_s[8192];
    __shared__ __align__(16) __bf16 attT_s[8192];
    __shared__ __align__(16) __bf16 pn_s[8192];
    __shared__ __align__(16) __bf16 pB_s[8192];
    __shared__ __align__(16) __bf16 Xa_s[1024];
    __shared__ __align__(16) __bf16 XaT_s[1024];
    __shared__ float red_s[128];
    __shared__ float invn_s[32];
    __shared__ float wred_s[4];

    const int v = blockIdx.x, t = blockIdx.y;
    const int tid = threadIdx.x;
    const int w = tid >> 6, l = tid & 63, q = l >> 4, n15 = l & 15;
    const int Av = att_nums[t];

    {
        const __bf16* s1 = an_frag + (size_t)t * 8192;
        const __bf16* s2 = attT_frag + (size_t)t * 8192;
        #pragma unroll
        for (int i = 0; i < 4; ++i) {
            const int slot = tid + 256 * i;
            *(bf16x8*)&an_s[slot * 8]   = *(const bf16x8*)&s1[slot * 8];
            *(bf16x8*)&attT_s[slot * 8] = *(const bf16x8*)&s2[slot * 8];
        }
    }
    __syncthreads();

    bf16x8 ab[4];
    #pragma unroll
    for (int n = 0; n < 4; ++n)
        ab[n] = *(const bf16x8*)&attT_s[((w * 4 + n) * 64 + l) * 8];

    f32x4 apacc[2][4];
    #pragma unroll
    for (int m = 0; m < 2; ++m)
        #pragma unroll
        for (int n = 0; n < 4; ++n) { f32x4 z = {0.f,0.f,0.f,0.f}; apacc[m][n] = z; }
    float sa_acc[4] = {0.f, 0.f, 0.f, 0.f};

    for (int c = 0; c < 6; ++c) {
        __syncthreads();
        {
            const __bf16* sp1 = pn_frag + (size_t)(v * 6 + c) * 8192;
            const __bf16* sp2 = pB_frag + (size_t)(v * 6 + c) * 8192;
            #pragma unroll
            for (int i = 0; i < 4; ++i) {
                const int slot = tid + 256 * i;
                *(bf16x8*)&pn_s[slot * 8] = *(const bf16x8*)&sp1[slot * 8];
                *(bf16x8*)&pB_s[slot * 8] = *(const bf16x8*)&sp2[slot * 8];
            }
        }
        __syncthreads();

        // ---- score: S=cos, X=exp(relu(20S)) masked, both frag layouts ----
        {
            const int mt = w >> 1, at = w & 1;
            f32x4 sacc = {0.f, 0.f, 0.f, 0.f};
            #pragma unroll
            for (int kp = 0; kp < 8; ++kp) {
                bf16x8 af  = *(const bf16x8*)&pn_s[((mt * 8 + kp) * 64 + l) * 8];
                bf16x8 bf_ = *(const bf16x8*)&an_s[((at * 8 + kp) * 64 + l) * 8];
                sacc = __builtin_amdgcn_mfma_f32_16x16x32_bf16(af, bf_, sacc, 0, 0, 0);
            }
            const int a = at * 16 + n15;
            #pragma unroll
            for (int r = 0; r < 4; ++r) {
                const int pcl = q * 4 + r;
                const int pcc = mt * 16 + pcl;
                float xvv = (a < Av) ? __expf(fmaxf(20.f * sacc[r], 0.f)) : 0.f;
                __bf16 h = (__bf16)xvv;
                Xa_s[mt * 512 + (pcl + 16 * (a >> 3)) * 8 + (a & 7)] = h;
                XaT_s[at * 512 + (n15 + 16 * (pcc >> 3)) * 8 + (pcc & 7)] = h;
            }
        }
        __syncthreads();

        // ---- aa = X·att, ap += X^T·patch ----
        f32x4 aacc[2][4];
        {
            bf16x8 xa0 = *(const bf16x8*)&Xa_s[l * 8];
            bf16x8 xa1 = *(const bf16x8*)&Xa_s[512 + l * 8];
            bf16x8 xt0 = *(const bf16x8*)&XaT_s[l * 8];
            bf16x8 xt1 = *(const bf16x8*)&XaT_s[512 + l * 8];
            #pragma unroll
            for (int n = 0; n < 4; ++n) {
                f32x4 z = {0.f, 0.f, 0.f, 0.f};
                aacc[0][n] = __builtin_amdgcn_mfma_f32_16x16x32_bf16(xa0, ab[n], z, 0, 0, 0);
                aacc[1][n] = __builtin_amdgcn_mfma_f32_16x16x32_bf16(xa1, ab[n], z, 0, 0, 0);
                bf16x8 pb = *(const bf16x8*)&pB_s[((w * 4 + n) * 64 + l) * 8];
                apacc[0][n] = __builtin_amdgcn_mfma_f32_16x16x32_bf16(xt0, pb, apacc[0][n], 0, 0, 0);
                apacc[1][n] = __builtin_amdgcn_mfma_f32_16x16x32_bf16(xt1, pb, apacc[1][n], 0, 0, 0);
            }
        }

        // ---- aa row norms + sa accumulation ----
        #pragma unroll
        for (int mt2 = 0; mt2 < 2; ++mt2)
            #pragma unroll
            for (int r = 0; r < 4; ++r) {
                float ssq = 0.f;
                #pragma unroll
                for (int n = 0; n < 4; ++n) { float vv = aacc[mt2][n][r]; ssq += vv * vv; }
                ssq += __shfl_xor(ssq, 1, 64);
                ssq += __shfl_xor(ssq, 2, 64);
                ssq += __shfl_xor(ssq, 4, 64);
                ssq += __shfl_xor(ssq, 8, 64);
                if (n15 == 0) red_s[(mt2 * 16 + q * 4 + r) * 4 + w] = ssq;
            }
        __syncthreads();
        if (tid < 32) {
            float s = red_s[tid * 4] + red_s[tid * 4 + 1] + red_s[tid * 4 + 2] + red_s[tid * 4 + 3];
            invn_s[tid] = 1.f / fmaxf(sqrtf(s), 1e-12f);
        }
        __syncthreads();
        #pragma unroll
        for (int mt2 = 0; mt2 < 2; ++mt2)
            #pragma unroll
            for (int r = 0; r < 4; ++r) {
                const float inr = invn_s[mt2 * 16 + q * 4 + r];
                #pragma unroll
                for (int n = 0; n < 4; ++n) sa_acc[n] += aacc[mt2][n][r] * inr;
            }
    }

    // ---- ap row norms ----
    #pragma unroll
    for (int mt2 = 0; mt2 < 2; ++mt2)
        #pragma unroll
        for (int r = 0; r < 4; ++r) {
            float ssq = 0.f;
            #pragma unroll
            for (int n = 0; n < 4; ++n) { float vv = apacc[mt2][n][r]; ssq += vv * vv; }
            ssq += __shfl_xor(ssq, 1, 64);
            ssq += __shfl_xor(ssq, 2, 64);
            ssq += __shfl_xor(ssq, 4, 64);
            ssq += __shfl_xor(ssq, 8, 64);
            if (n15 == 0) red_s[(mt2 * 16 + q * 4 + r) * 4 + w] = ssq;
        }
    __syncthreads();
    if (tid < 32) {
        float s = red_s[tid * 4] + red_s[tid * 4 + 1] + red_s[tid * 4 + 2] + red_s[tid * 4 + 3];
        invn_s[tid] = 1.f / fmaxf(sqrtf(s), 1e-12f);
    }
    __syncthreads();

    // ---- rank-1 contraction ----
    float prod = 0.f;
    #pragma unroll
    for (int n = 0; n < 4; ++n) {
        float sp = 0.f;
        #pragma unroll
        for (int mt2 = 0; mt2 < 2; ++mt2)
            #pragma unroll
            for (int r = 0; r < 4; ++r)
                sp += apacc[mt2][n][r] * invn_s[mt2 * 16 + q * 4 + r];
        float saf = sa_acc[n];
        saf += __shfl_xor(saf, 16, 64);
        saf += __shfl_xor(saf, 32, 64);
        float spf = sp;
        spf += __shfl_xor(spf, 16, 64);
        spf += __shfl_xor(spf, 32, 64);
        prod += saf * spf;
    }
    prod += __shfl_xor(prod, 1, 64);
    prod += __shfl_xor(prod, 2, 64);
    prod += __shfl_xor(prod, 4, 64);
    prod += __shfl_xor(prod, 8, 64);
    prod += __shfl_xor(prod, 16, 64);
    prod += __shfl_xor(prod, 32, 64);
    if (l == 0) wred_s[w] = prod;
    __syncthreads();
    if (tid == 0)
        out_sim[t * NB + v] = (wred_s[0] + wred_s[1] + wred_s[2] + wred_s[3]) * 0.25f
                              / ((float)Av * 30.f);
}

// ---------------------------------------------------------------------------
extern "C" void kernel_launch(void* const* d_in, const int* in_sizes, int n_in,
                              void* d_out, int out_size, void* d_ws, size_t ws_size,
                              hipStream_t stream)
{
    const float* vf = (const float*)d_in[0];
    const float* tf = (const float*)d_in[1];
    const int*   an = (const int*)d_in[3];
    const float* Wv = (const float*)d_in[4];
    const float* bv = (const float*)d_in[5];
    const float* Wt = (const float*)d_in[6];
    const float* bt = (const float*)d_in[7];
    const float* Wp = (const float*)d_in[8];
    const float* bp = (const float*)d_in[9];
    const float* Wa = (const float*)d_in[10];
    const float* ba = (const float*)d_in[11];

    float* out = (float*)d_out;
    float* out_vis = out;
    float* out_txt = out + 8192;
    float* out_pm  = out + 16384;
    float* out_am  = out + 24576;
    float* out_sim = out + 32768;

    __bf16* wsb = (__bf16*)d_ws;
    __bf16* pn_frag   = wsb;                 // 32*6*8192 = 1,572,864 elems
    __bf16* pB_frag   = wsb + 1572864;       // 1,572,864 elems
    __bf16* an_frag   = wsb + 3145728;       // 32*8192 = 262,144
    __bf16* attT_frag = wsb + 3407872;       // 262,144  (total 7,340,032 B)

    // out_pm accumulated via atomics -> zero it (poisoned 0xAA before each call)
    hipMemsetAsync((char*)d_out + 16384 * sizeof(float), 0, 8192 * sizeof(float), stream);

    proj_fused_kernel<<<226, 256, 0, stream>>>(
        vf, tf, Wv, bv, Wt, bt, Wp, bp, Wa, ba, an,
        out_vis, out_txt, out_pm, out_am,
        pn_frag, pB_frag, an_frag, attT_frag);

    pair_mfma_kernel<<<dim3(NB, NB), 256, 0, stream>>>(
        pn_frag, pB_frag, an_frag, attT_frag, an, out_sim);
}